// Round 5
// baseline (161.650 us; speedup 1.0000x reference)
//
#include <hip/hip_runtime.h>
#include <stdint.h>

#define NBATCH   8
#define NA       261888
#define PRE      6000
#define PREP     6016
#define NCHUNK   94
#define OUT_CNT  2000
#define NMS_THR  0.7f
#define NBINS    4096
#define CANDCAP  8192
#define ECAP     8
#define SEGCAP   2048
#define J0       3072     // edges computed only for j < J0; scan falls back past it
#define NTPE     24       // tile-pairs: jt0->4, jt1->8, jt2->12 i-tiles

// workspace layout (bytes)
#define OFF_HIST     0ull                      // 8*4096*4 = 131072
#define OFF_BCNT     131072ull                 // 8*4096*4 = 131072
#define OFF_CNT      262144ull                 // 8*6016*4 = 192512
#define ZEND         454656ull
#define OFF_TINFO    454656ull                 // 32
#define OFF_CUM      454688ull                 // 8*4097*4 = 131104
#define OFF_BOXES    585792ull                 // 8*6016*16 = 770048
#define OFF_CANDS    1355840ull                // 8*8192*8 = 524288
#define OFF_EDGES    1355840ull                // overlays candS (dead after binsort): 770048
// total ~2.03 MB

__device__ __forceinline__ int score_bin(float s) {
    int b = (int)(s * 4096.0f);          // *4096 exact (pow2) -> monotone
    return min(max(b, 0), NBINS - 1);
}

// ---------------- K1: per-batch histogram of score bins ----------------
__global__ void k_hist(const float* __restrict__ probs, uint32_t* __restrict__ hist) {
    __shared__ uint32_t h[NBINS];
    int b = blockIdx.y;
    for (int i = threadIdx.x; i < NBINS; i += blockDim.x) h[i] = 0;
    __syncthreads();
    const float4* p4 = (const float4*)(probs + (size_t)b * NA * 2);
    const int total = NA / 2;
    const int stride = gridDim.x * blockDim.x;
    for (int q = blockIdx.x * blockDim.x + threadIdx.x; q < total; q += stride) {
        float4 v = p4[q];
        atomicAdd(&h[score_bin(v.y)], 1u);
        atomicAdd(&h[score_bin(v.w)], 1u);
    }
    __syncthreads();
    uint32_t* gh = hist + b * NBINS;
    for (int i = threadIdx.x; i < NBINS; i += blockDim.x)
        if (h[i]) atomicAdd(&gh[i], h[i]);
}

// ---------------- K2: threshold bin T + suffix cumulative counts ----------------
__global__ void k_select(const uint32_t* __restrict__ hist, uint32_t* __restrict__ tinfo,
                         uint32_t* __restrict__ cum) {
    int b = blockIdx.x;
    const uint32_t* gh = hist + b * NBINS;
    uint32_t* gc = cum + (size_t)b * (NBINS + 1);
    __shared__ uint32_t cs[256];
    __shared__ int tbin;
    int t = threadIdx.x;
    uint32_t loc[16];
    uint32_t s = 0;
    for (int i = 0; i < 16; ++i) { loc[i] = gh[t * 16 + i]; s += loc[i]; }
    cs[t] = s;
    if (t == 0) tbin = 0;
    __syncthreads();
    if (t == 0) {
        uint32_t acc = 0;
        for (int c = 255; c >= 0; --c) { uint32_t v = cs[c]; cs[c] = acc; acc += v; }
    }
    __syncthreads();
    uint32_t acc = cs[t];
    int localT = -1;
    for (int i = 15; i >= 0; --i) {
        int bin = t * 16 + i;
        acc += loc[i];
        gc[bin] = acc;
        if (localT < 0 && acc >= PRE) localT = bin;
    }
    if (t == 255) gc[NBINS] = 0;
    if (localT >= 0) atomicMax(&tbin, localT);
    __syncthreads();
    if (t == 0) tinfo[b] = (uint32_t)tbin;
}

// ---------------- K3: compact directly into bin segments (per-bin atomics) ----------------
__global__ void k_compactD(const float* __restrict__ probs, const uint32_t* __restrict__ tinfo,
                           const uint32_t* __restrict__ cum, uint32_t* __restrict__ bcnt,
                           uint64_t* __restrict__ candS) {
    int b = blockIdx.y;
    int T = (int)tinfo[b];
    const uint32_t* gc = cum + (size_t)b * (NBINS + 1);
    uint32_t* bc = bcnt + (size_t)b * NBINS;
    uint64_t* cs = candS + (size_t)b * CANDCAP;
    const float4* p4 = (const float4*)(probs + (size_t)b * NA * 2);
    const int total = NA / 2;
    const int stride = gridDim.x * blockDim.x;
    for (int q = blockIdx.x * blockDim.x + threadIdx.x; q < total; q += stride) {
        float4 v = p4[q];
        #pragma unroll
        for (int k = 0; k < 2; ++k) {
            float s = k ? v.w : v.y;
            int anchor = 2 * q + k;
            int bin = score_bin(s);
            if (bin >= T) {
                uint32_t r = atomicAdd(&bc[bin], 1u);
                uint32_t pos = gc[bin + 1] + r;
                if (pos < CANDCAP) {
                    uint32_t sb = __float_as_uint(s);
                    cs[pos] = ((uint64_t)(~sb) << 32) | (uint32_t)anchor;
                }
            }
        }
    }
}

// ---------------- K4: per-bin sort + gather + transform ----------------
__global__ __launch_bounds__(256) void k_binsort(
        const uint64_t* __restrict__ candS, const uint32_t* __restrict__ tinfo,
        const uint32_t* __restrict__ hist, const uint32_t* __restrict__ cum,
        const float* __restrict__ rpn_bbox, const float* __restrict__ anchors,
        float* __restrict__ boxes) {
    __shared__ uint64_t key[SEGCAP];
    int b = blockIdx.y;
    int T = (int)tinfo[b];
    const uint32_t* gh = hist + b * NBINS;
    const uint32_t* gc = cum + (size_t)b * (NBINS + 1);
    const uint64_t* cs = candS + (size_t)b * CANDCAP;
    const float4* an4 = (const float4*)(anchors + (size_t)b * NA * 4);
    const float4* bb4 = (const float4*)(rpn_bbox + (size_t)b * NA * 4);
    float4* bx = (float4*)(boxes) + (size_t)b * PREP;

    for (int bin = T + blockIdx.x; bin < NBINS; bin += gridDim.x) {
        int n = (int)gh[bin];
        if (n == 0) continue;
        if (n > SEGCAP) n = SEGCAP;
        uint32_t base = gc[bin + 1];
        if (base >= PRE) continue;
        int P = 1; while (P < n) P <<= 1;
        for (int i = threadIdx.x; i < P; i += 256)
            key[i] = (i < n) ? cs[base + i] : ~0ull;
        __syncthreads();
        for (int k = 2; k <= P; k <<= 1) {
            for (int j = k >> 1; j > 0; j >>= 1) {
                for (int i = threadIdx.x; i < P; i += 256) {
                    int ixj = i ^ j;
                    if (ixj > i) {
                        uint64_t a = key[i], c = key[ixj];
                        bool up = ((i & k) == 0);
                        if ((a > c) == up) { key[i] = c; key[ixj] = a; }
                    }
                }
                __syncthreads();
            }
        }
        for (int r = threadIdx.x; r < n; r += 256) {
            uint32_t pos = base + (uint32_t)r;
            if (pos < PRE) {
                uint32_t aidx = (uint32_t)(key[r] & 0xFFFFFFFFu);
                float4 a = an4[aidx];
                float4 d = bb4[aidx];
                float dy = d.x * 0.1f, dx = d.y * 0.1f, dh = d.z * 0.2f, dw = d.w * 0.2f;
                float h = a.z - a.x, w = a.w - a.y;
                float cy = a.x + 0.5f * h;  cy = cy + dy * h;
                float cx = a.y + 0.5f * w;  cx = cx + dx * w;
                h = h * expf(dh);
                w = w * expf(dw);
                float y1 = cy - 0.5f * h, x1 = cx - 0.5f * w;
                float y2 = y1 + h, x2 = x1 + w;
                float4 o;
                o.x = fminf(fmaxf(y1, 0.f), 1.f);
                o.y = fminf(fmaxf(x1, 0.f), 1.f);
                o.z = fminf(fmaxf(y2, 0.f), 1.f);
                o.w = fminf(fmaxf(x2, 0.f), 1.f);
                bx[pos] = o;
            }
        }
        __syncthreads();
    }
}

// ---------------- K5: overlap edges, 4 j-boxes/thread in regs, i-tile in LDS ----------------
// Pre-filter: IoU>0.7 => inter > 0.7*area_j; gate with 0.6*area_j (safe slack),
// exact division test only on the rare (~4%/wave) path.
__global__ __launch_bounds__(256) void k_edges(const float* __restrict__ boxes,
                                               uint32_t* __restrict__ cnt,
                                               uint16_t* __restrict__ edges) {
    int b = blockIdx.y;
    int t = blockIdx.x;
    int jt, it;
    if (t < 4)       { jt = 0; it = t; }
    else if (t < 12) { jt = 1; it = t - 4; }
    else             { jt = 2; it = t - 12; }
    int ibase = it * 256, jbase = jt * 1024;
    bool diag = (ibase + 256 > jbase);
    __shared__ float4 sb[256];
    const float4* bx = (const float4*)(boxes) + (size_t)b * PREP;
    sb[threadIdx.x] = bx[ibase + threadIdx.x];
    __syncthreads();
    int gj0 = jbase + threadIdx.x;
    float4 Jb0 = bx[gj0];
    float4 Jb1 = bx[gj0 + 256];
    float4 Jb2 = bx[gj0 + 512];
    float4 Jb3 = bx[gj0 + 768];
    float th0 = 0.6f * ((Jb0.z - Jb0.x) * (Jb0.w - Jb0.y));
    float th1 = 0.6f * ((Jb1.z - Jb1.x) * (Jb1.w - Jb1.y));
    float th2 = 0.6f * ((Jb2.z - Jb2.x) * (Jb2.w - Jb2.y));
    float th3 = 0.6f * ((Jb3.z - Jb3.x) * (Jb3.w - Jb3.y));
    uint32_t* cb = cnt + (size_t)b * PREP;
    uint16_t* eb = edges + (size_t)b * PREP * ECAP;

#define EVAL(Jb, thr, gjv) {                                                  \
        float yy1 = fmaxf((Jb).x, I.x), xx1 = fmaxf((Jb).y, I.y);             \
        float yy2 = fminf((Jb).z, I.z), xx2 = fminf((Jb).w, I.w);             \
        float ih = fmaxf(yy2 - yy1, 0.f), iw = fmaxf(xx2 - xx1, 0.f);         \
        float inter = ih * iw;                                                \
        if (inter > (thr)) {                                                  \
            if (!diag || gi < (gjv)) {                                        \
                float ai = (I.z - I.x) * (I.w - I.y);                         \
                float aj = ((Jb).z - (Jb).x) * ((Jb).w - (Jb).y);             \
                float uni = (ai + aj) - inter;                                \
                float iou = inter / uni;                                      \
                if (iou > NMS_THR) {                                          \
                    uint32_t slot = atomicAdd(&cb[(gjv)], 1u);                \
                    if (slot < ECAP) eb[(size_t)(gjv) * ECAP + slot] = (uint16_t)gi; \
                }                                                             \
            }                                                                 \
        }                                                                     \
    }

    float4 I  = sb[0];
    float4 Ip = sb[1];
    #pragma unroll 2
    for (int itr = 0; itr < 256; ++itr) {
        float4 In = sb[(itr + 2) & 255];   // prefetch 2 ahead (wraps harmlessly)
        int gi = ibase + itr;
        EVAL(Jb0, th0, gj0);
        EVAL(Jb1, th1, gj0 + 256);
        EVAL(Jb2, th2, gj0 + 512);
        EVAL(Jb3, th3, gj0 + 768);
        I = Ip;
        Ip = In;
    }
#undef EVAL
}

// ---------------- K6: keep-scan, lane-parallel resolution ----------------
__device__ __forceinline__ float iou_of(float4 A, float4 Bv) {
    float ai = (A.z - A.x) * (A.w - A.y);
    float aj = (Bv.z - Bv.x) * (Bv.w - Bv.y);
    float yy1 = fmaxf(A.x, Bv.x), xx1 = fmaxf(A.y, Bv.y);
    float yy2 = fminf(A.z, Bv.z), xx2 = fminf(A.w, Bv.w);
    float inter = fmaxf(yy2 - yy1, 0.f) * fmaxf(xx2 - xx1, 0.f);
    float uni = (ai + aj) - inter;
    return (uni > 0.f) ? inter / uni : 0.f;
}

__global__ __launch_bounds__(256) void k_scan(const float* __restrict__ boxes,
                                              const uint32_t* __restrict__ cnt,
                                              const uint16_t* __restrict__ edges,
                                              float* __restrict__ out) {
    int b = blockIdx.x;
    __shared__ uint8_t  cl[PREP];
    __shared__ uint32_t pr[PREP];
    __shared__ uint64_t km[NCHUNK];
    __shared__ uint16_t list[OUT_CNT];
    __shared__ int kcs;
    int tid = threadIdx.x;
    const uint32_t* cb = cnt + (size_t)b * PREP;
    const uint32_t* eb32 = (const uint32_t*)(edges + (size_t)b * PREP * ECAP);
    const uint4*    eb128 = (const uint4*)(edges + (size_t)b * PREP * ECAP);
    #pragma unroll 4
    for (int j = tid; j < PREP; j += 256) {
        uint32_t c = cb[j];
        cl[j] = (j < J0) ? (uint8_t)(c > 255u ? 255u : c) : (uint8_t)255;  // 255 = unknown
        pr[j] = eb32[j * 4];   // slots 0,1
    }
    __syncthreads();
    const float4* bx = (const float4*)(boxes) + (size_t)b * PREP;
    if (tid < 64) {
        int lane = tid;
        int kc = 0;
        for (int c0 = 0; c0 < NCHUNK; ++c0) {
            int base = c0 * 64;
            int j = base + lane;
            bool valid = j < PRE;
            uint64_t word = __ballot(valid);
            int cv = valid ? (int)cl[j] : 0;
            uint32_t prv = pr[j];
            uint4 ev = make_uint4(0u, 0u, 0u, 0u);
            bool manym = (cv >= 3 && cv <= ECAP);
            if (__ballot(manym)) { if (manym) ev = eb128[j]; }
            bool same = false, supB = false;
            bool hard = valid && (cv > ECAP);
            if (valid && cv > 0 && cv <= ECAP) {
                if (cv <= 2) {
                    int p0 = (int)(prv & 0xFFFFu);
                    int p1 = (int)(prv >> 16);
                    bool s1 = (cv == 2) && (p1 >= base);
                    same = (p0 >= base) || s1;
                    if (!same) {
                        supB = ((km[p0 >> 6] >> (p0 & 63)) & 1ull) != 0ull;
                        if (!supB && cv == 2)
                            supB = ((km[p1 >> 6] >> (p1 & 63)) & 1ull) != 0ull;
                    }
                } else {
                    int es[8] = { (int)(ev.x & 0xFFFFu), (int)(ev.x >> 16),
                                  (int)(ev.y & 0xFFFFu), (int)(ev.y >> 16),
                                  (int)(ev.z & 0xFFFFu), (int)(ev.z >> 16),
                                  (int)(ev.w & 0xFFFFu), (int)(ev.w >> 16) };
                    #pragma unroll
                    for (int k = 0; k < 8; ++k)
                        if (k < cv) same = same || (es[k] >= base);
                    if (!same) {
                        #pragma unroll
                        for (int k = 0; k < 8; ++k)
                            if (k < cv && !supB)
                                supB = ((km[es[k] >> 6] >> (es[k] & 63)) & 1ull) != 0ull;
                    }
                }
            }
            word &= ~__ballot(supB);
            uint64_t fix = __ballot(same || hard);
            while (fix) {
                int p = __ffsll((unsigned long long)fix) - 1;
                fix &= fix - 1;
                int jp = base + p;
                int cvp = __shfl(cv, p);
                bool sup = false;
                if (cvp <= ECAP) {
                    uint32_t prp = (uint32_t)__shfl((int)prv, p);
                    uint32_t evx = (uint32_t)__shfl((int)ev.x, p);
                    uint32_t evy = (uint32_t)__shfl((int)ev.y, p);
                    uint32_t evz = (uint32_t)__shfl((int)ev.z, p);
                    uint32_t evw = (uint32_t)__shfl((int)ev.w, p);
                    int es[8];
                    if (cvp <= 2) {
                        es[0] = (int)(prp & 0xFFFFu); es[1] = (int)(prp >> 16);
                        es[2] = es[3] = es[4] = es[5] = es[6] = es[7] = 0;
                    } else {
                        es[0] = (int)(evx & 0xFFFFu); es[1] = (int)(evx >> 16);
                        es[2] = (int)(evy & 0xFFFFu); es[3] = (int)(evy >> 16);
                        es[4] = (int)(evz & 0xFFFFu); es[5] = (int)(evz >> 16);
                        es[6] = (int)(evw & 0xFFFFu); es[7] = (int)(evw >> 16);
                    }
                    #pragma unroll
                    for (int k = 0; k < 8; ++k) {
                        if (k < cvp && !sup) {
                            int e = es[k];
                            bool kept = (e >= base)
                                ? (((word >> (e - base)) & 1ull) != 0ull)
                                : (((km[e >> 6] >> (e & 63)) & 1ull) != 0ull);
                            sup = sup || kept;
                        }
                    }
                } else {
                    float4 J = bx[jp];
                    bool any = false;
                    for (int t2 = lane; t2 < kc; t2 += 64)
                        if (iou_of(bx[list[t2]], J) > NMS_THR) any = true;
                    if (lane < p && ((word >> lane) & 1ull))
                        if (iou_of(bx[base + lane], J) > NMS_THR) any = true;
                    sup = (__ballot(any) != 0ull);
                }
                if (sup) word &= ~(1ull << p);
            }
            km[c0] = word;
            int pos = kc + __popcll(word & ((1ull << lane) - 1ull));
            if (((word >> lane) & 1ull) && pos < OUT_CNT) list[pos] = (uint16_t)j;
            kc += __popcll(word);
            if (kc >= OUT_CNT) { kc = OUT_CNT; break; }
        }
        if (lane == 0) kcs = kc;
    }
    __syncthreads();
    int kc = kcs;
    float4* ob = (float4*)(out) + (size_t)b * OUT_CNT;
    for (int r = tid; r < OUT_CNT; r += 256) {
        float4 o = make_float4(0.f, 0.f, 0.f, 0.f);
        if (r < kc) o = bx[list[r]];
        ob[r] = o;
    }
}

extern "C" void kernel_launch(void* const* d_in, const int* in_sizes, int n_in,
                              void* d_out, int out_size, void* d_ws, size_t ws_size,
                              hipStream_t stream) {
    const float* probs   = (const float*)d_in[0];
    const float* rpnbbox = (const float*)d_in[1];
    const float* anchors = (const float*)d_in[2];
    float* out = (float*)d_out;
    char* ws = (char*)d_ws;

    uint32_t* hist   = (uint32_t*)(ws + OFF_HIST);
    uint32_t* bcnt   = (uint32_t*)(ws + OFF_BCNT);
    uint32_t* cnt    = (uint32_t*)(ws + OFF_CNT);
    uint32_t* tinfo  = (uint32_t*)(ws + OFF_TINFO);
    uint32_t* cum    = (uint32_t*)(ws + OFF_CUM);
    float*    boxes  = (float*)(ws + OFF_BOXES);
    uint64_t* candS  = (uint64_t*)(ws + OFF_CANDS);
    uint16_t* edges  = (uint16_t*)(ws + OFF_EDGES);

    hipMemsetAsync(ws, 0, (size_t)ZEND, stream);

    k_hist<<<dim3(64, NBATCH), 256, 0, stream>>>(probs, hist);
    k_select<<<NBATCH, 256, 0, stream>>>(hist, tinfo, cum);
    k_compactD<<<dim3(64, NBATCH), 256, 0, stream>>>(probs, tinfo, cum, bcnt, candS);
    k_binsort<<<dim3(128, NBATCH), 256, 0, stream>>>(candS, tinfo, hist, cum, rpnbbox, anchors, boxes);
    k_edges<<<dim3(NTPE, NBATCH), 256, 0, stream>>>(boxes, cnt, edges);
    k_scan<<<NBATCH, 256, 0, stream>>>(boxes, cnt, edges, out);
}

// Round 6
// 121.945 us; speedup vs baseline: 1.3256x; 1.3256x over previous
//
#include <hip/hip_runtime.h>
#include <stdint.h>

#define NBATCH   8
#define NA       261888
#define PRE      6000
#define PREP     6016
#define NCHUNK   94
#define OUT_CNT  2000
#define NMS_THR  0.7f
#define NBINS    4096
#define CANDCAP  8192
#define ECAP     8
#define SEGCAP   2048
#define J0       3072     // edges computed only for j < J0; scan falls back past it
#define NJT      12       // J0 / 256
#define NTPE     78       // NJT*(NJT+1)/2 tile-pairs

// workspace layout (bytes)
#define OFF_HIST     0ull                      // 8*4096*4 = 131072
#define OFF_BCNT     131072ull                 // 8*4096*4 = 131072
#define OFF_CNT      262144ull                 // 8*6016*4 = 192512
#define ZEND         454656ull
#define OFF_TINFO    454656ull                 // 32
#define OFF_CUM      454688ull                 // 8*4097*4 = 131104
#define OFF_BOXES    585792ull                 // 8*6016*16 = 770048
#define OFF_CANDS    1355840ull                // 8*8192*8 = 524288
#define OFF_EDGES    1355840ull                // overlays candS (dead after binsort): 770048
// total ~2.03 MB

__device__ __forceinline__ int score_bin(float s) {
    int b = (int)(s * 4096.0f);          // *4096 exact (pow2) -> monotone
    return min(max(b, 0), NBINS - 1);
}

// ---------------- K1: per-batch histogram of score bins ----------------
__global__ void k_hist(const float* __restrict__ probs, uint32_t* __restrict__ hist) {
    __shared__ uint32_t h[NBINS];
    int b = blockIdx.y;
    for (int i = threadIdx.x; i < NBINS; i += blockDim.x) h[i] = 0;
    __syncthreads();
    const float4* p4 = (const float4*)(probs + (size_t)b * NA * 2);
    const int total = NA / 2;
    const int stride = gridDim.x * blockDim.x;
    for (int q = blockIdx.x * blockDim.x + threadIdx.x; q < total; q += stride) {
        float4 v = p4[q];
        atomicAdd(&h[score_bin(v.y)], 1u);
        atomicAdd(&h[score_bin(v.w)], 1u);
    }
    __syncthreads();
    uint32_t* gh = hist + b * NBINS;
    for (int i = threadIdx.x; i < NBINS; i += blockDim.x)
        if (h[i]) atomicAdd(&gh[i], h[i]);
}

// ---------------- K2: threshold bin T + suffix cumulative counts ----------------
__global__ void k_select(const uint32_t* __restrict__ hist, uint32_t* __restrict__ tinfo,
                         uint32_t* __restrict__ cum) {
    int b = blockIdx.x;
    const uint32_t* gh = hist + b * NBINS;
    uint32_t* gc = cum + (size_t)b * (NBINS + 1);
    __shared__ uint32_t cs[256];
    __shared__ int tbin;
    int t = threadIdx.x;
    uint32_t loc[16];
    uint32_t s = 0;
    for (int i = 0; i < 16; ++i) { loc[i] = gh[t * 16 + i]; s += loc[i]; }
    cs[t] = s;
    if (t == 0) tbin = 0;
    __syncthreads();
    if (t == 0) {
        uint32_t acc = 0;
        for (int c = 255; c >= 0; --c) { uint32_t v = cs[c]; cs[c] = acc; acc += v; }
    }
    __syncthreads();
    uint32_t acc = cs[t];
    int localT = -1;
    for (int i = 15; i >= 0; --i) {
        int bin = t * 16 + i;
        acc += loc[i];
        gc[bin] = acc;
        if (localT < 0 && acc >= PRE) localT = bin;
    }
    if (t == 255) gc[NBINS] = 0;
    if (localT >= 0) atomicMax(&tbin, localT);
    __syncthreads();
    if (t == 0) tinfo[b] = (uint32_t)tbin;
}

// ---------------- K3: compact directly into bin segments (per-bin atomics) ----------------
__global__ void k_compactD(const float* __restrict__ probs, const uint32_t* __restrict__ tinfo,
                           const uint32_t* __restrict__ cum, uint32_t* __restrict__ bcnt,
                           uint64_t* __restrict__ candS) {
    int b = blockIdx.y;
    int T = (int)tinfo[b];
    const uint32_t* gc = cum + (size_t)b * (NBINS + 1);
    uint32_t* bc = bcnt + (size_t)b * NBINS;
    uint64_t* cs = candS + (size_t)b * CANDCAP;
    const float4* p4 = (const float4*)(probs + (size_t)b * NA * 2);
    const int total = NA / 2;
    const int stride = gridDim.x * blockDim.x;
    for (int q = blockIdx.x * blockDim.x + threadIdx.x; q < total; q += stride) {
        float4 v = p4[q];
        #pragma unroll
        for (int k = 0; k < 2; ++k) {
            float s = k ? v.w : v.y;
            int anchor = 2 * q + k;
            int bin = score_bin(s);
            if (bin >= T) {
                uint32_t r = atomicAdd(&bc[bin], 1u);
                uint32_t pos = gc[bin + 1] + r;
                if (pos < CANDCAP) {
                    uint32_t sb = __float_as_uint(s);
                    cs[pos] = ((uint64_t)(~sb) << 32) | (uint32_t)anchor;
                }
            }
        }
    }
}

// ---------------- K4: per-bin sort + gather + transform ----------------
__global__ __launch_bounds__(256) void k_binsort(
        const uint64_t* __restrict__ candS, const uint32_t* __restrict__ tinfo,
        const uint32_t* __restrict__ hist, const uint32_t* __restrict__ cum,
        const float* __restrict__ rpn_bbox, const float* __restrict__ anchors,
        float* __restrict__ boxes) {
    __shared__ uint64_t key[SEGCAP];
    int b = blockIdx.y;
    int T = (int)tinfo[b];
    const uint32_t* gh = hist + b * NBINS;
    const uint32_t* gc = cum + (size_t)b * (NBINS + 1);
    const uint64_t* cs = candS + (size_t)b * CANDCAP;
    const float4* an4 = (const float4*)(anchors + (size_t)b * NA * 4);
    const float4* bb4 = (const float4*)(rpn_bbox + (size_t)b * NA * 4);
    float4* bx = (float4*)(boxes) + (size_t)b * PREP;

    for (int bin = T + blockIdx.x; bin < NBINS; bin += gridDim.x) {
        int n = (int)gh[bin];
        if (n == 0) continue;
        if (n > SEGCAP) n = SEGCAP;
        uint32_t base = gc[bin + 1];
        if (base >= PRE) continue;
        int P = 1; while (P < n) P <<= 1;
        for (int i = threadIdx.x; i < P; i += 256)
            key[i] = (i < n) ? cs[base + i] : ~0ull;
        __syncthreads();
        for (int k = 2; k <= P; k <<= 1) {
            for (int j = k >> 1; j > 0; j >>= 1) {
                for (int i = threadIdx.x; i < P; i += 256) {
                    int ixj = i ^ j;
                    if (ixj > i) {
                        uint64_t a = key[i], c = key[ixj];
                        bool up = ((i & k) == 0);
                        if ((a > c) == up) { key[i] = c; key[ixj] = a; }
                    }
                }
                __syncthreads();
            }
        }
        for (int r = threadIdx.x; r < n; r += 256) {
            uint32_t pos = base + (uint32_t)r;
            if (pos < PRE) {
                uint32_t aidx = (uint32_t)(key[r] & 0xFFFFFFFFu);
                float4 a = an4[aidx];
                float4 d = bb4[aidx];
                float dy = d.x * 0.1f, dx = d.y * 0.1f, dh = d.z * 0.2f, dw = d.w * 0.2f;
                float h = a.z - a.x, w = a.w - a.y;
                float cy = a.x + 0.5f * h;  cy = cy + dy * h;
                float cx = a.y + 0.5f * w;  cx = cx + dx * w;
                h = h * expf(dh);
                w = w * expf(dw);
                float y1 = cy - 0.5f * h, x1 = cx - 0.5f * w;
                float y2 = y1 + h, x2 = x1 + w;
                float4 o;
                o.x = fminf(fmaxf(y1, 0.f), 1.f);
                o.y = fminf(fmaxf(x1, 0.f), 1.f);
                o.z = fminf(fmaxf(y2, 0.f), 1.f);
                o.w = fminf(fmaxf(x2, 0.f), 1.f);
                bx[pos] = o;
            }
        }
        __syncthreads();
    }
}

// ---------------- K5: overlap edges — r4 grid (624 blocks) + r5 inner loop ----------------
// Thread owns one j (box+threshold in regs); 256-box i-tile broadcast from LDS.
// Gate: IoU>0.7 => inter > 0.7*union >= 0.7*area_j; use 0.6*area_j (slack safe
// against float rounding). Exact reference-order division test inside rare branch.
__global__ __launch_bounds__(256) void k_edges(const float* __restrict__ boxes,
                                               uint32_t* __restrict__ cnt,
                                               uint16_t* __restrict__ edges) {
    int b = blockIdx.y;
    int t = blockIdx.x;
    int ti = 0, rem = t;
    while (rem >= NJT - ti) { rem -= NJT - ti; ++ti; }
    int tj = ti + rem;                       // ti <= tj < NJT
    __shared__ float4 sb[256];
    const float4* bx = (const float4*)(boxes) + (size_t)b * PREP;
    sb[threadIdx.x] = bx[ti * 256 + threadIdx.x];
    __syncthreads();
    int gj = tj * 256 + threadIdx.x;
    float4 Jb = bx[gj];
    float jy1 = Jb.x, jx1 = Jb.y, jy2 = Jb.z, jx2 = Jb.w;
    float aj = (jy2 - jy1) * (jx2 - jx1);
    float thr = 0.6f * aj;
    bool diag = (ti == tj);
    uint32_t* cb = cnt + (size_t)b * PREP;
    uint16_t* eb = edges + (size_t)b * PREP * ECAP;
    int gibase = ti * 256;
    #pragma unroll 4
    for (int it = 0; it < 256; ++it) {
        float4 I = sb[it];                   // broadcast, conflict-free
        float yy1 = fmaxf(jy1, I.x), xx1 = fmaxf(jx1, I.y);
        float yy2 = fminf(jy2, I.z), xx2 = fminf(jx2, I.w);
        float ih = fmaxf(yy2 - yy1, 0.f), iw = fmaxf(xx2 - xx1, 0.f);
        float inter = ih * iw;
        if (inter > thr) {                   // rare (~10% of wave-iters)
            int gi = gibase + it;
            if (!diag || gi < gj) {
                float ai = (I.z - I.x) * (I.w - I.y);
                float uni = (ai + aj) - inter;   // reference op order
                float iou = inter / uni;
                if (iou > NMS_THR) {
                    uint32_t slot = atomicAdd(&cb[gj], 1u);
                    if (slot < ECAP) eb[(size_t)gj * ECAP + slot] = (uint16_t)gi;
                }
            }
        }
    }
}

// ---------------- K6: keep-scan, lane-parallel resolution ----------------
__device__ __forceinline__ float iou_of(float4 A, float4 Bv) {
    float ai = (A.z - A.x) * (A.w - A.y);
    float aj = (Bv.z - Bv.x) * (Bv.w - Bv.y);
    float yy1 = fmaxf(A.x, Bv.x), xx1 = fmaxf(A.y, Bv.y);
    float yy2 = fminf(A.z, Bv.z), xx2 = fminf(A.w, Bv.w);
    float inter = fmaxf(yy2 - yy1, 0.f) * fmaxf(xx2 - xx1, 0.f);
    float uni = (ai + aj) - inter;
    return (uni > 0.f) ? inter / uni : 0.f;
}

__global__ __launch_bounds__(256) void k_scan(const float* __restrict__ boxes,
                                              const uint32_t* __restrict__ cnt,
                                              const uint16_t* __restrict__ edges,
                                              float* __restrict__ out) {
    int b = blockIdx.x;
    __shared__ uint8_t  cl[PREP];
    __shared__ uint32_t pr[PREP];
    __shared__ uint64_t km[NCHUNK];
    __shared__ uint16_t list[OUT_CNT];
    __shared__ int kcs;
    int tid = threadIdx.x;
    const uint32_t* cb = cnt + (size_t)b * PREP;
    const uint32_t* eb32 = (const uint32_t*)(edges + (size_t)b * PREP * ECAP);
    const uint4*    eb128 = (const uint4*)(edges + (size_t)b * PREP * ECAP);
    #pragma unroll 4
    for (int j = tid; j < PREP; j += 256) {
        uint32_t c = cb[j];
        cl[j] = (j < J0) ? (uint8_t)(c > 255u ? 255u : c) : (uint8_t)255;  // 255 = unknown
        pr[j] = eb32[j * 4];   // slots 0,1
    }
    __syncthreads();
    const float4* bx = (const float4*)(boxes) + (size_t)b * PREP;
    if (tid < 64) {
        int lane = tid;
        int kc = 0;
        for (int c0 = 0; c0 < NCHUNK; ++c0) {
            int base = c0 * 64;
            int j = base + lane;
            bool valid = j < PRE;
            uint64_t word = __ballot(valid);
            int cv = valid ? (int)cl[j] : 0;
            uint32_t prv = pr[j];
            uint4 ev = make_uint4(0u, 0u, 0u, 0u);
            bool manym = (cv >= 3 && cv <= ECAP);
            if (__ballot(manym)) { if (manym) ev = eb128[j]; }
            bool same = false, supB = false;
            bool hard = valid && (cv > ECAP);
            if (valid && cv > 0 && cv <= ECAP) {
                if (cv <= 2) {
                    int p0 = (int)(prv & 0xFFFFu);
                    int p1 = (int)(prv >> 16);
                    bool s1 = (cv == 2) && (p1 >= base);
                    same = (p0 >= base) || s1;
                    if (!same) {
                        supB = ((km[p0 >> 6] >> (p0 & 63)) & 1ull) != 0ull;
                        if (!supB && cv == 2)
                            supB = ((km[p1 >> 6] >> (p1 & 63)) & 1ull) != 0ull;
                    }
                } else {
                    int es[8] = { (int)(ev.x & 0xFFFFu), (int)(ev.x >> 16),
                                  (int)(ev.y & 0xFFFFu), (int)(ev.y >> 16),
                                  (int)(ev.z & 0xFFFFu), (int)(ev.z >> 16),
                                  (int)(ev.w & 0xFFFFu), (int)(ev.w >> 16) };
                    #pragma unroll
                    for (int k = 0; k < 8; ++k)
                        if (k < cv) same = same || (es[k] >= base);
                    if (!same) {
                        #pragma unroll
                        for (int k = 0; k < 8; ++k)
                            if (k < cv && !supB)
                                supB = ((km[es[k] >> 6] >> (es[k] & 63)) & 1ull) != 0ull;
                    }
                }
            }
            word &= ~__ballot(supB);
            uint64_t fix = __ballot(same || hard);
            while (fix) {
                int p = __ffsll((unsigned long long)fix) - 1;
                fix &= fix - 1;
                int jp = base + p;
                int cvp = __shfl(cv, p);
                bool sup = false;
                if (cvp <= ECAP) {
                    uint32_t prp = (uint32_t)__shfl((int)prv, p);
                    uint32_t evx = (uint32_t)__shfl((int)ev.x, p);
                    uint32_t evy = (uint32_t)__shfl((int)ev.y, p);
                    uint32_t evz = (uint32_t)__shfl((int)ev.z, p);
                    uint32_t evw = (uint32_t)__shfl((int)ev.w, p);
                    int es[8];
                    if (cvp <= 2) {
                        es[0] = (int)(prp & 0xFFFFu); es[1] = (int)(prp >> 16);
                        es[2] = es[3] = es[4] = es[5] = es[6] = es[7] = 0;
                    } else {
                        es[0] = (int)(evx & 0xFFFFu); es[1] = (int)(evx >> 16);
                        es[2] = (int)(evy & 0xFFFFu); es[3] = (int)(evy >> 16);
                        es[4] = (int)(evz & 0xFFFFu); es[5] = (int)(evz >> 16);
                        es[6] = (int)(evw & 0xFFFFu); es[7] = (int)(evw >> 16);
                    }
                    #pragma unroll
                    for (int k = 0; k < 8; ++k) {
                        if (k < cvp && !sup) {
                            int e = es[k];
                            bool kept = (e >= base)
                                ? (((word >> (e - base)) & 1ull) != 0ull)
                                : (((km[e >> 6] >> (e & 63)) & 1ull) != 0ull);
                            sup = sup || kept;
                        }
                    }
                } else {
                    float4 J = bx[jp];
                    bool any = false;
                    for (int t2 = lane; t2 < kc; t2 += 64)
                        if (iou_of(bx[list[t2]], J) > NMS_THR) any = true;
                    if (lane < p && ((word >> lane) & 1ull))
                        if (iou_of(bx[base + lane], J) > NMS_THR) any = true;
                    sup = (__ballot(any) != 0ull);
                }
                if (sup) word &= ~(1ull << p);
            }
            km[c0] = word;
            int pos = kc + __popcll(word & ((1ull << lane) - 1ull));
            if (((word >> lane) & 1ull) && pos < OUT_CNT) list[pos] = (uint16_t)j;
            kc += __popcll(word);
            if (kc >= OUT_CNT) { kc = OUT_CNT; break; }
        }
        if (lane == 0) kcs = kc;
    }
    __syncthreads();
    int kc = kcs;
    float4* ob = (float4*)(out) + (size_t)b * OUT_CNT;
    for (int r = tid; r < OUT_CNT; r += 256) {
        float4 o = make_float4(0.f, 0.f, 0.f, 0.f);
        if (r < kc) o = bx[list[r]];
        ob[r] = o;
    }
}

extern "C" void kernel_launch(void* const* d_in, const int* in_sizes, int n_in,
                              void* d_out, int out_size, void* d_ws, size_t ws_size,
                              hipStream_t stream) {
    const float* probs   = (const float*)d_in[0];
    const float* rpnbbox = (const float*)d_in[1];
    const float* anchors = (const float*)d_in[2];
    float* out = (float*)d_out;
    char* ws = (char*)d_ws;

    uint32_t* hist   = (uint32_t*)(ws + OFF_HIST);
    uint32_t* bcnt   = (uint32_t*)(ws + OFF_BCNT);
    uint32_t* cnt    = (uint32_t*)(ws + OFF_CNT);
    uint32_t* tinfo  = (uint32_t*)(ws + OFF_TINFO);
    uint32_t* cum    = (uint32_t*)(ws + OFF_CUM);
    float*    boxes  = (float*)(ws + OFF_BOXES);
    uint64_t* candS  = (uint64_t*)(ws + OFF_CANDS);
    uint16_t* edges  = (uint16_t*)(ws + OFF_EDGES);

    hipMemsetAsync(ws, 0, (size_t)ZEND, stream);

    k_hist<<<dim3(64, NBATCH), 256, 0, stream>>>(probs, hist);
    k_select<<<NBATCH, 256, 0, stream>>>(hist, tinfo, cum);
    k_compactD<<<dim3(64, NBATCH), 256, 0, stream>>>(probs, tinfo, cum, bcnt, candS);
    k_binsort<<<dim3(128, NBATCH), 256, 0, stream>>>(candS, tinfo, hist, cum, rpnbbox, anchors, boxes);
    k_edges<<<dim3(NTPE, NBATCH), 256, 0, stream>>>(boxes, cnt, edges);
    k_scan<<<NBATCH, 256, 0, stream>>>(boxes, cnt, edges, out);
}